// Round 1
// baseline (6789.223 us; speedup 1.0000x reference)
//
#include <hip/hip_runtime.h>
#include <math.h>

// AxialLinearAttention — fp32 correctness-first baseline.
// B=256, FG=4, ANT=32, D=1024, H=16, DK=64, L1=ANT=32 (1024 batches), L2=FG=4 (8192 batches).
// Flat token count M = 32768 for every projection GEMM.

#define MTOT 32768
#define DM 1024

#define ACT_NONE 0
#define ACT_ELU1 1
#define REMAP_NONE 0
#define REMAP_A2F 1   // stage-1 row r=(b,fg,ant) -> stage-2 row s=(b,ant,fg)
#define REMAP_F2O 2   // stage-2 row s=(b,ant,fg) -> output row r=(b,fg,ant)

// C[srow][n] = act(A[m][:] @ W[:][n] + bias[n]) (+ resid[m][n])
// 128x128 tile, BK=16, 256 threads, 8x8 per thread.
template<int ACT, int REMAP, bool RES>
__global__ __launch_bounds__(256) void gemm_k(
    const float* __restrict__ A, const float* __restrict__ W,
    const float* __restrict__ bias, const float* __restrict__ resid,
    float* __restrict__ C)
{
  __shared__ float AsT[16][128];  // A tile transposed: AsT[k][row]
  __shared__ float Bs[16][128];   // W tile: Bs[k][col]

  const int t  = threadIdx.x;
  const int tx = t & 15, ty = t >> 4;
  const int m0 = blockIdx.x * 128, n0 = blockIdx.y * 128;

  const int arow = t >> 1, ak = (t & 1) * 8;        // A loads: 2 lanes per row
  const int brow = t >> 4, bcol = (t & 15) * 8;     // W loads: 16 lanes per row

  const float* Aptr = A + (size_t)(m0 + arow) * DM + ak;
  const float* Wptr = W + (size_t)brow * DM + n0 + bcol;

  float acc[8][8] = {};

  for (int k0 = 0; k0 < DM; k0 += 16) {
    float4 a0 = *(const float4*)(Aptr + k0);
    float4 a1 = *(const float4*)(Aptr + k0 + 4);
    float4 b0 = *(const float4*)(Wptr + (size_t)k0 * DM);
    float4 b1 = *(const float4*)(Wptr + (size_t)k0 * DM + 4);
    __syncthreads();  // previous iter's LDS reads complete before overwrite
    AsT[ak + 0][arow] = a0.x; AsT[ak + 1][arow] = a0.y;
    AsT[ak + 2][arow] = a0.z; AsT[ak + 3][arow] = a0.w;
    AsT[ak + 4][arow] = a1.x; AsT[ak + 5][arow] = a1.y;
    AsT[ak + 6][arow] = a1.z; AsT[ak + 7][arow] = a1.w;
    *(float4*)&Bs[brow][bcol]     = b0;
    *(float4*)&Bs[brow][bcol + 4] = b1;
    __syncthreads();
#pragma unroll
    for (int kk = 0; kk < 16; ++kk) {
      float4 a04 = *(float4*)&AsT[kk][ty * 8];
      float4 a14 = *(float4*)&AsT[kk][ty * 8 + 4];
      float4 b04 = *(float4*)&Bs[kk][tx * 8];
      float4 b14 = *(float4*)&Bs[kk][tx * 8 + 4];
      float av[8] = {a04.x, a04.y, a04.z, a04.w, a14.x, a14.y, a14.z, a14.w};
      float bv[8] = {b04.x, b04.y, b04.z, b04.w, b14.x, b14.y, b14.z, b14.w};
#pragma unroll
      for (int i = 0; i < 8; ++i)
#pragma unroll
        for (int j = 0; j < 8; ++j)
          acc[i][j] = fmaf(av[i], bv[j], acc[i][j]);
    }
  }

#pragma unroll
  for (int i = 0; i < 8; ++i) {
    const int m = m0 + ty * 8 + i;  // logical row
    int srow;
    if (REMAP == REMAP_NONE) {
      srow = m;
    } else if (REMAP == REMAP_A2F) {
      int b = m >> 7, fg = (m >> 5) & 3, ant = m & 31;
      srow = b * 128 + ant * 4 + fg;
    } else {
      int b = m >> 7, ant = (m >> 2) & 31, fg = m & 3;
      srow = b * 128 + fg * 32 + ant;
    }
    float v[8];
#pragma unroll
    for (int j = 0; j < 8; ++j) {
      float val = acc[i][j] + bias[n0 + tx * 8 + j];
      if (RES) val += resid[(size_t)m * DM + n0 + tx * 8 + j];
      if (ACT == ACT_ELU1) val = (val > 0.f) ? (val + 1.f) : expf(val);  // elu(x)+1
      v[j] = val;
    }
    float4* dst = (float4*)(C + (size_t)srow * DM + n0 + tx * 8);
    dst[0] = make_float4(v[0], v[1], v[2], v[3]);
    dst[1] = make_float4(v[4], v[5], v[6], v[7]);
  }
}

// One block per (batch g, head h): KV[64][64] = sum_t K[t][d]*V[t][e]; att = Q @ KV.
// att overwrites Q's (g,h) slice in place (block-private region).
template<int L>
__global__ __launch_bounds__(256) void linattn_k(
    float* __restrict__ Q, const float* __restrict__ K, const float* __restrict__ V)
{
  __shared__ float QsT[64][L + 1];  // transposed + pad: att-phase reads conflict-free
  __shared__ float Ks[L][64];
  __shared__ float Vs[L][64];
  __shared__ float KV[64][68];      // pad 4 floats: spreads write banks

  const int g = blockIdx.x, h = blockIdx.y;
  const size_t base = (size_t)g * L * DM + (size_t)h * 64;
  const int t = threadIdx.x;

  for (int idx = t * 4; idx < L * 64; idx += 1024) {
    int tt = idx >> 6, d = idx & 63;
    float4 q4 = *(const float4*)(Q + base + (size_t)tt * DM + d);
    float4 k4 = *(const float4*)(K + base + (size_t)tt * DM + d);
    float4 v4 = *(const float4*)(V + base + (size_t)tt * DM + d);
    QsT[d + 0][tt] = q4.x; QsT[d + 1][tt] = q4.y;
    QsT[d + 2][tt] = q4.z; QsT[d + 3][tt] = q4.w;
    *(float4*)&Ks[tt][d] = k4;
    *(float4*)&Vs[tt][d] = v4;
  }
  __syncthreads();

  {  // KV: thread owns (d, 16 e's)
    const int d = t >> 2, eb = (t & 3) * 16;
    float kv[16] = {};
    for (int tt = 0; tt < L; ++tt) {
      float kk = Ks[tt][d];
      const float4* vr = (const float4*)&Vs[tt][eb];
      float4 v0 = vr[0], v1 = vr[1], v2 = vr[2], v3 = vr[3];
      kv[0]  = fmaf(kk, v0.x, kv[0]);  kv[1]  = fmaf(kk, v0.y, kv[1]);
      kv[2]  = fmaf(kk, v0.z, kv[2]);  kv[3]  = fmaf(kk, v0.w, kv[3]);
      kv[4]  = fmaf(kk, v1.x, kv[4]);  kv[5]  = fmaf(kk, v1.y, kv[5]);
      kv[6]  = fmaf(kk, v1.z, kv[6]);  kv[7]  = fmaf(kk, v1.w, kv[7]);
      kv[8]  = fmaf(kk, v2.x, kv[8]);  kv[9]  = fmaf(kk, v2.y, kv[9]);
      kv[10] = fmaf(kk, v2.z, kv[10]); kv[11] = fmaf(kk, v2.w, kv[11]);
      kv[12] = fmaf(kk, v3.x, kv[12]); kv[13] = fmaf(kk, v3.y, kv[13]);
      kv[14] = fmaf(kk, v3.z, kv[14]); kv[15] = fmaf(kk, v3.w, kv[15]);
    }
#pragma unroll
    for (int e4 = 0; e4 < 4; ++e4)
      *(float4*)&KV[d][eb + e4 * 4] =
          make_float4(kv[e4 * 4], kv[e4 * 4 + 1], kv[e4 * 4 + 2], kv[e4 * 4 + 3]);
  }
  __syncthreads();

  {  // att[t][e] = sum_d Q[t][d] * KV[d][e]
    constexpr int P = (L * 64) / 256;  // outputs per thread: L=32 -> 8, L=4 -> 1
    const int ob = t * P;
    const int tt = ob >> 6, e0 = ob & 63;
    float outv[P] = {};
    for (int dd = 0; dd < 64; ++dd) {
      float q = QsT[dd][tt];
#pragma unroll
      for (int p = 0; p < P; ++p) outv[p] = fmaf(q, KV[dd][e0 + p], outv[p]);
    }
#pragma unroll
    for (int p = 0; p < P; ++p) Q[base + (size_t)tt * DM + e0 + p] = outv[p];
  }
}

extern "C" void kernel_launch(void* const* d_in, const int* in_sizes, int n_in,
                              void* d_out, int out_size, void* d_ws, size_t ws_size,
                              hipStream_t stream)
{
  const float* x   = (const float*)d_in[0];
  const float* aqw = (const float*)d_in[1];  const float* aqb = (const float*)d_in[2];
  const float* akw = (const float*)d_in[3];  const float* akb = (const float*)d_in[4];
  const float* avw = (const float*)d_in[5];  const float* avb = (const float*)d_in[6];
  const float* aow = (const float*)d_in[7];  const float* aob = (const float*)d_in[8];
  const float* fqw = (const float*)d_in[9];  const float* fqb = (const float*)d_in[10];
  const float* fkw = (const float*)d_in[11]; const float* fkb = (const float*)d_in[12];
  const float* fvw = (const float*)d_in[13]; const float* fvb = (const float*)d_in[14];
  const float* fow = (const float*)d_in[15]; const float* fob = (const float*)d_in[16];
  float* out = (float*)d_out;

  const size_t NE = (size_t)MTOT * DM;  // 33,554,432 elements per buffer
  float* Qb = (float*)d_ws;
  float* Kb = Qb + NE;
  float* Vb = Kb + NE;
  const bool big = ws_size >= 4 * NE * sizeof(float);
  float* X2 = big ? (Vb + NE) : out;  // small-ws path: X2 lives in d_out

  dim3 gg(MTOT / 128, DM / 128), gb(256);

  // ----- stage 1: antenna attention (1024 batches x L=32) -----
  gemm_k<ACT_ELU1, REMAP_NONE, false><<<gg, gb, 0, stream>>>(x, aqw, aqb, nullptr, Qb);
  gemm_k<ACT_ELU1, REMAP_NONE, false><<<gg, gb, 0, stream>>>(x, akw, akb, nullptr, Kb);
  gemm_k<ACT_NONE, REMAP_NONE, false><<<gg, gb, 0, stream>>>(x, avw, avb, nullptr, Vb);
  linattn_k<32><<<dim3(1024, 16), gb, 0, stream>>>(Qb, Kb, Vb);
  // Y1 = x + att@Wout, stored transposed (b,ant,fg) into X2
  gemm_k<ACT_NONE, REMAP_A2F, true><<<gg, gb, 0, stream>>>(Qb, aow, aob, x, X2);

  // ----- stage 2: frequency attention (8192 batches x L=4) -----
  gemm_k<ACT_ELU1, REMAP_NONE, false><<<gg, gb, 0, stream>>>(X2, fqw, fqb, nullptr, Qb);
  gemm_k<ACT_ELU1, REMAP_NONE, false><<<gg, gb, 0, stream>>>(X2, fkw, fkb, nullptr, Kb);
  gemm_k<ACT_NONE, REMAP_NONE, false><<<gg, gb, 0, stream>>>(X2, fvw, fvb, nullptr, Vb);
  linattn_k<4><<<dim3(8192, 16), gb, 0, stream>>>(Qb, Kb, Vb);
  // Y2 = X2 + att2@Wout2, stored back in (b,fg,ant) order
  if (big) {
    gemm_k<ACT_NONE, REMAP_F2O, true><<<gg, gb, 0, stream>>>(Qb, fow, fob, X2, out);
  } else {
    gemm_k<ACT_NONE, REMAP_F2O, true><<<gg, gb, 0, stream>>>(Qb, fow, fob, X2, Kb);
    hipMemcpyAsync(out, Kb, NE * sizeof(float), hipMemcpyDeviceToDevice, stream);
  }
}

// Round 2
// 1616.757 us; speedup vs baseline: 4.1993x; 4.1993x over previous
//
#include <hip/hip_runtime.h>
#include <math.h>

// AxialLinearAttention — fp16 MFMA version (m97-structure GEMMs).
// B=256, FG=4, ANT=32, D=1024, H=16, DK=64. M = 32768 rows for every GEMM.
// Scale bookkeeping (all powers of 2, exact):
//   xh = x               (fp16, scale 1)
//   Q1,K1,V1             (fp16, scale 1)
//   att1 stored * 2^-4
//   X2f fp32 (in d_out), X2h = X2 * 2^-4 (fp16, reuses xh buffer)
//   Q2,K2,V2 stored * 2^-4
//   att2 stored * 2^-16  (acc 2^-12 from scaled inputs, * 2^-4 on store)
//   final: 2^16 * acc + bias + X2f

#define MTOT 32768
#define DM 1024

using half8   = __attribute__((ext_vector_type(8))) _Float16;
using floatx4 = __attribute__((ext_vector_type(4))) float;

#define ACT_NONE 0
#define ACT_ELU1 1
#define REMAP_NONE 0
#define REMAP_A2F 1   // (b,fg,ant) -> (b,ant,fg)
#define REMAP_F2O 2   // (b,ant,fg) -> (b,fg,ant)

__device__ __forceinline__ void gload16(const void* g, void* lds) {
  __builtin_amdgcn_global_load_lds(
      (const __attribute__((address_space(1))) unsigned int*)g,
      (__attribute__((address_space(3))) unsigned int*)lds, 16, 0, 0);
}

// C = act(sin_s * (A @ Wt^T) + bias [+ resid]); rows remapped on store.
// A: [M][1024] fp16 K-major. Wt: [N][1024] fp16 K-major (pre-transposed W).
// 128x128 tile, BK=32, 256 threads (4 waves), wave -> 64x64, mfma 16x16x32 f16.
// LDS tiles [128 rows][32 k] fp16, 64B rows; XOR swizzle: 16B slot ^= (row>>1)&3
// applied on the global SOURCE during global_load_lds staging (linear LDS dest)
// and on the ds_read address (both-sides involution).
template<int ACT, int REMAP, bool RES, bool OF32, bool OF16>
__global__ __launch_bounds__(256) void gemm_k(
    const _Float16* __restrict__ A, const _Float16* __restrict__ W,
    const float* __restrict__ bias, const float* __restrict__ resid,
    float* __restrict__ Cf, _Float16* __restrict__ Ch,
    float sin_s, float sout_s)
{
  __shared__ _Float16 As[4096];  // 8 KB
  __shared__ _Float16 Bs[4096];

  const int t = threadIdx.x, w = t >> 6, l = t & 63;
  const int m0 = blockIdx.x * 128, n0 = blockIdx.y * 128;
  const int lr = l & 15, ls = l >> 4;
  const int wrow = (w >> 1) * 64, wcol = (w & 1) * 64;

  // staging: 8 chunks of 1024B per tile; wave w owns chunks w*2, w*2+1.
  // linear LDS byte = u*1024 + l*16 -> row = u*16 + (l>>2), slot = l&3;
  // fetch global kslot = slot ^ ((row>>1)&3).
  int srow_[2], skof_[2];
#pragma unroll
  for (int i = 0; i < 2; ++i) {
    int u = w * 2 + i;
    int row = u * 16 + (l >> 2);
    srow_[i] = row;
    skof_[i] = ((l & 3) ^ ((row >> 1) & 3)) * 8;
  }
  // LDS frag byte offsets (k0-independent)
  int aoff[4], boff[4];
#pragma unroll
  for (int m = 0; m < 4; ++m) {
    int ra = wrow + m * 16 + lr;
    aoff[m] = ra * 64 + ((ls ^ ((ra >> 1) & 3)) << 4);
    int rb = wcol + m * 16 + lr;
    boff[m] = rb * 64 + ((ls ^ ((rb >> 1) & 3)) << 4);
  }

  floatx4 acc[4][4];
#pragma unroll
  for (int m = 0; m < 4; ++m)
#pragma unroll
    for (int n = 0; n < 4; ++n) acc[m][n] = (floatx4)0.f;

  const char* AsC = (const char*)As;
  const char* BsC = (const char*)Bs;

  for (int k0 = 0; k0 < DM; k0 += 32) {
    if (k0) __syncthreads();  // previous tile's readers done
#pragma unroll
    for (int i = 0; i < 2; ++i) {
      int u = w * 2 + i;
      gload16(A + (size_t)(m0 + srow_[i]) * DM + k0 + skof_[i], (char*)As + u * 1024);
      gload16(W + (size_t)(n0 + srow_[i]) * DM + k0 + skof_[i], (char*)Bs + u * 1024);
    }
    __syncthreads();  // vmcnt drained by compiler before barrier -> tile ready

    half8 af[4], bf[4];
#pragma unroll
    for (int m = 0; m < 4; ++m) af[m] = *(const half8*)(AsC + aoff[m]);
#pragma unroll
    for (int n = 0; n < 4; ++n) bf[n] = *(const half8*)(BsC + boff[n]);
#pragma unroll
    for (int m = 0; m < 4; ++m)
#pragma unroll
      for (int n = 0; n < 4; ++n)
        acc[m][n] = __builtin_amdgcn_mfma_f32_16x16x32_f16(af[m], bf[n], acc[m][n], 0, 0, 0);
  }

  // epilogue phase 1: finalize values in acc (C/D map: row=(l>>4)*4+j, col=l&15)
#pragma unroll
  for (int m = 0; m < 4; ++m)
#pragma unroll
    for (int n = 0; n < 4; ++n)
#pragma unroll
      for (int j = 0; j < 4; ++j) {
        int rt = wrow + m * 16 + ls * 4 + j;
        int ct = wcol + n * 16 + lr;
        float v = acc[m][n][j] * sin_s + bias[n0 + ct];
        if (RES) v += resid[(size_t)(m0 + rt) * DM + n0 + ct];
        if (ACT == ACT_ELU1) v = (v > 0.f) ? (v + 1.f) : expf(v);
        acc[m][n][j] = v;
      }
  // F2O reads resid from the same buffer region it writes (in-block row
  // permutation) -> all reads must complete before any store.
  if (REMAP == REMAP_F2O) __syncthreads();

#pragma unroll
  for (int m = 0; m < 4; ++m)
#pragma unroll
    for (int n = 0; n < 4; ++n)
#pragma unroll
      for (int j = 0; j < 4; ++j) {
        int rt = wrow + m * 16 + ls * 4 + j;
        int ct = wcol + n * 16 + lr;
        int mg = m0 + rt, ng = n0 + ct;
        int srw;
        if (REMAP == REMAP_NONE) {
          srw = mg;
        } else if (REMAP == REMAP_A2F) {
          int b = mg >> 7, fg = (mg >> 5) & 3, ant = mg & 31;
          srw = b * 128 + ant * 4 + fg;
        } else {
          int b = mg >> 7, ant = (mg >> 2) & 31, fg = mg & 3;
          srw = b * 128 + fg * 32 + ant;
        }
        float v = acc[m][n][j];
        if (OF32) Cf[(size_t)srw * DM + ng] = v;
        if (OF16) Ch[(size_t)srw * DM + ng] = (_Float16)(v * sout_s);
      }
}

// One block per (batch g, head h): KV = K^T V (fp32 in LDS), att = Q @ KV.
// fp16 I/O; att overwrites Q's slice (block-private). Store scaled by sout.
template<int L>
__global__ __launch_bounds__(256) void linattn_k(
    _Float16* __restrict__ Q, const _Float16* __restrict__ K,
    const _Float16* __restrict__ V, float sout)
{
  __shared__ float QsT[64][L + 1];
  __shared__ float Ks[L][64];
  __shared__ float Vs[L][64];
  __shared__ float KV[64][68];

  const int g = blockIdx.x, h = blockIdx.y;
  const size_t base = (size_t)g * L * DM + (size_t)h * 64;
  const int t = threadIdx.x;

  for (int idx = t * 8; idx < L * 64; idx += 2048) {
    int tt = idx >> 6, d = idx & 63;
    half8 q8 = *(const half8*)(Q + base + (size_t)tt * DM + d);
    half8 k8 = *(const half8*)(K + base + (size_t)tt * DM + d);
    half8 v8 = *(const half8*)(V + base + (size_t)tt * DM + d);
#pragma unroll
    for (int e = 0; e < 8; ++e) {
      QsT[d + e][tt] = (float)q8[e];
      Ks[tt][d + e]  = (float)k8[e];
      Vs[tt][d + e]  = (float)v8[e];
    }
  }
  __syncthreads();

  {  // KV: thread owns (d, 16 e's)
    const int d = t >> 2, eb = (t & 3) * 16;
    float kv[16] = {};
    for (int tt = 0; tt < L; ++tt) {
      float kk = Ks[tt][d];
      const float4* vr = (const float4*)&Vs[tt][eb];
      float4 v0 = vr[0], v1 = vr[1], v2 = vr[2], v3 = vr[3];
      kv[0]  = fmaf(kk, v0.x, kv[0]);  kv[1]  = fmaf(kk, v0.y, kv[1]);
      kv[2]  = fmaf(kk, v0.z, kv[2]);  kv[3]  = fmaf(kk, v0.w, kv[3]);
      kv[4]  = fmaf(kk, v1.x, kv[4]);  kv[5]  = fmaf(kk, v1.y, kv[5]);
      kv[6]  = fmaf(kk, v1.z, kv[6]);  kv[7]  = fmaf(kk, v1.w, kv[7]);
      kv[8]  = fmaf(kk, v2.x, kv[8]);  kv[9]  = fmaf(kk, v2.y, kv[9]);
      kv[10] = fmaf(kk, v2.z, kv[10]); kv[11] = fmaf(kk, v2.w, kv[11]);
      kv[12] = fmaf(kk, v3.x, kv[12]); kv[13] = fmaf(kk, v3.y, kv[13]);
      kv[14] = fmaf(kk, v3.z, kv[14]); kv[15] = fmaf(kk, v3.w, kv[15]);
    }
#pragma unroll
    for (int e4 = 0; e4 < 4; ++e4)
      *(float4*)&KV[d][eb + e4 * 4] =
          make_float4(kv[e4 * 4], kv[e4 * 4 + 1], kv[e4 * 4 + 2], kv[e4 * 4 + 3]);
  }
  __syncthreads();

  {  // att[t][e] = sum_d Q[t][d] * KV[d][e]; store fp16 * sout
    constexpr int P = (L * 64) / 256;
    const int ob = t * P;
    const int tt = ob >> 6, e0 = ob & 63;
    float outv[P] = {};
    for (int dd = 0; dd < 64; ++dd) {
      float q = QsT[dd][tt];
#pragma unroll
      for (int p = 0; p < P; ++p) outv[p] = fmaf(q, KV[dd][e0 + p], outv[p]);
    }
#pragma unroll
    for (int p = 0; p < P; ++p)
      Q[base + (size_t)tt * DM + e0 + p] = (_Float16)(outv[p] * sout);
  }
}

// Wt[n][k] = (fp16) W[k][n], 1024x1024.
__global__ __launch_bounds__(256) void transpose_w_k(
    const float* __restrict__ W, _Float16* __restrict__ Wt)
{
  __shared__ float tile[32][33];
  const int tx = threadIdx.x & 31, ty = threadIdx.x >> 5;
  const int k0 = blockIdx.x * 32, n0 = blockIdx.y * 32;
#pragma unroll
  for (int r = 0; r < 4; ++r)
    tile[ty + r * 8][tx] = W[(size_t)(k0 + ty + r * 8) * DM + n0 + tx];
  __syncthreads();
#pragma unroll
  for (int r = 0; r < 4; ++r)
    Wt[(size_t)(n0 + ty + r * 8) * DM + k0 + tx] = (_Float16)tile[tx][ty + r * 8];
}

__global__ __launch_bounds__(256) void convf2h_k(
    const float* __restrict__ x, _Float16* __restrict__ xh, int n8)
{
  for (int i = blockIdx.x * blockDim.x + threadIdx.x; i < n8;
       i += gridDim.x * blockDim.x) {
    float4 a = ((const float4*)x)[i * 2];
    float4 b = ((const float4*)x)[i * 2 + 1];
    half8 h;
    h[0] = (_Float16)a.x; h[1] = (_Float16)a.y; h[2] = (_Float16)a.z; h[3] = (_Float16)a.w;
    h[4] = (_Float16)b.x; h[5] = (_Float16)b.y; h[6] = (_Float16)b.z; h[7] = (_Float16)b.w;
    ((half8*)xh)[i] = h;
  }
}

extern "C" void kernel_launch(void* const* d_in, const int* in_sizes, int n_in,
                              void* d_out, int out_size, void* d_ws, size_t ws_size,
                              hipStream_t stream)
{
  const float* x   = (const float*)d_in[0];
  const float* wsrc[8] = {(const float*)d_in[1], (const float*)d_in[3],
                          (const float*)d_in[5], (const float*)d_in[7],
                          (const float*)d_in[9], (const float*)d_in[11],
                          (const float*)d_in[13], (const float*)d_in[15]};
  const float* aqb = (const float*)d_in[2];  const float* akb = (const float*)d_in[4];
  const float* avb = (const float*)d_in[6];  const float* aob = (const float*)d_in[8];
  const float* fqb = (const float*)d_in[10]; const float* fkb = (const float*)d_in[12];
  const float* fvb = (const float*)d_in[14]; const float* fob = (const float*)d_in[16];
  float* out = (float*)d_out;

  const size_t NE = (size_t)MTOT * DM;
  _Float16* xh = (_Float16*)d_ws;     // also reused as X2h after stage 1
  _Float16* Qh = xh + NE;             // att overwrites Q in place
  _Float16* Kh = Qh + NE;
  _Float16* Vh = Kh + NE;
  _Float16* wt = Vh + NE;             // 8 x 1M halves
  const size_t WSZ = (size_t)DM * DM;

  dim3 gg(MTOT / 128, DM / 128), gb(256);
  dim3 tg(32, 32);

  convf2h_k<<<2048, gb, 0, stream>>>(x, xh, (int)(NE / 8));
  for (int j = 0; j < 8; ++j)
    transpose_w_k<<<tg, gb, 0, stream>>>(wsrc[j], wt + WSZ * j);

  const float S = 0.0625f;  // 2^-4

  // ----- stage 1: antenna attention -----
  gemm_k<ACT_ELU1, REMAP_NONE, false, false, true><<<gg, gb, 0, stream>>>(
      xh, wt + WSZ * 0, aqb, nullptr, nullptr, Qh, 1.f, 1.f);
  gemm_k<ACT_ELU1, REMAP_NONE, false, false, true><<<gg, gb, 0, stream>>>(
      xh, wt + WSZ * 1, akb, nullptr, nullptr, Kh, 1.f, 1.f);
  gemm_k<ACT_NONE, REMAP_NONE, false, false, true><<<gg, gb, 0, stream>>>(
      xh, wt + WSZ * 2, avb, nullptr, nullptr, Vh, 1.f, 1.f);
  linattn_k<32><<<dim3(1024, 16), gb, 0, stream>>>(Qh, Kh, Vh, S);
  // X2 = x + att1*2^4 @ Wout: fp32 into d_out, fp16*2^-4 into xh; rows (b,ant,fg)
  gemm_k<ACT_NONE, REMAP_A2F, true, true, true><<<gg, gb, 0, stream>>>(
      Qh, wt + WSZ * 3, aob, x, out, xh, 16.f, S);

  // ----- stage 2: frequency attention -----
  gemm_k<ACT_ELU1, REMAP_NONE, false, false, true><<<gg, gb, 0, stream>>>(
      xh, wt + WSZ * 4, fqb, nullptr, nullptr, Qh, 16.f, S);
  gemm_k<ACT_ELU1, REMAP_NONE, false, false, true><<<gg, gb, 0, stream>>>(
      xh, wt + WSZ * 5, fkb, nullptr, nullptr, Kh, 16.f, S);
  gemm_k<ACT_NONE, REMAP_NONE, false, false, true><<<gg, gb, 0, stream>>>(
      xh, wt + WSZ * 6, fvb, nullptr, nullptr, Vh, 16.f, S);
  linattn_k<4><<<dim3(8192, 16), gb, 0, stream>>>(Qh, Kh, Vh, S);
  // out = X2f + att2*2^16 @ Wout2, rows back to (b,fg,ant); in-place over d_out
  gemm_k<ACT_NONE, REMAP_F2O, true, true, false><<<gg, gb, 0, stream>>>(
      Qh, wt + WSZ * 7, fob, out, out, nullptr, 65536.f, 1.f);
}

// Round 3
// 1189.646 us; speedup vs baseline: 5.7069x; 1.3590x over previous
//
#include <hip/hip_runtime.h>
#include <math.h>

// AxialLinearAttention — fp16 MFMA GEMMs + re-associated (QK^T)V linear attention.
// B=256, FG=4, ANT=32, D=1024, H=16, DK=64. M = 32768 rows for every GEMM.
// Scale bookkeeping (all powers of 2, exact):
//   xh = x (fp16, scale 1); Q1,K1,V1 scale 1; att1 stored * 2^-4
//   X2f fp32 (d_out), X2h = X2 * 2^-4 (reuses xh); Q2,K2,V2 stored * 2^-4
//   att2 stored * 2^-16; final: 2^16 * acc + bias + X2f

#define MTOT 32768
#define DM 1024

using half8   = __attribute__((ext_vector_type(8))) _Float16;
using h2      = __attribute__((ext_vector_type(2))) _Float16;
using floatx4 = __attribute__((ext_vector_type(4))) float;

#define ACT_NONE 0
#define ACT_ELU1 1
#define REMAP_NONE 0
#define REMAP_A2F 1   // (b,fg,ant) -> (b,ant,fg)
#define REMAP_F2O 2   // (b,ant,fg) -> (b,fg,ant)

__device__ __forceinline__ void gload16(const void* g, void* lds) {
  __builtin_amdgcn_global_load_lds(
      (const __attribute__((address_space(1))) unsigned int*)g,
      (__attribute__((address_space(3))) unsigned int*)lds, 16, 0, 0);
}

__device__ __forceinline__ float fdot2f(h2 a, h2 b, float c) {
#if __has_builtin(__builtin_amdgcn_fdot2)
  return __builtin_amdgcn_fdot2(a, b, c, false);
#else
  return fmaf((float)a[0], (float)b[0], fmaf((float)a[1], (float)b[1], c));
#endif
}

// ---------------- GEMM (unchanged from round 2) ----------------
// C = act(sin_s * (A @ Wt^T) + bias [+ resid]); rows remapped on store.
template<int ACT, int REMAP, bool RES, bool OF32, bool OF16>
__global__ __launch_bounds__(256) void gemm_k(
    const _Float16* __restrict__ A, const _Float16* __restrict__ W,
    const float* __restrict__ bias, const float* __restrict__ resid,
    float* __restrict__ Cf, _Float16* __restrict__ Ch,
    float sin_s, float sout_s)
{
  __shared__ _Float16 As[4096];
  __shared__ _Float16 Bs[4096];

  const int t = threadIdx.x, w = t >> 6, l = t & 63;
  const int m0 = blockIdx.x * 128, n0 = blockIdx.y * 128;
  const int lr = l & 15, ls = l >> 4;
  const int wrow = (w >> 1) * 64, wcol = (w & 1) * 64;

  int srow_[2], skof_[2];
#pragma unroll
  for (int i = 0; i < 2; ++i) {
    int u = w * 2 + i;
    int row = u * 16 + (l >> 2);
    srow_[i] = row;
    skof_[i] = ((l & 3) ^ ((row >> 1) & 3)) * 8;
  }
  int aoff[4], boff[4];
#pragma unroll
  for (int m = 0; m < 4; ++m) {
    int ra = wrow + m * 16 + lr;
    aoff[m] = ra * 64 + ((ls ^ ((ra >> 1) & 3)) << 4);
    int rb = wcol + m * 16 + lr;
    boff[m] = rb * 64 + ((ls ^ ((rb >> 1) & 3)) << 4);
  }

  floatx4 acc[4][4];
#pragma unroll
  for (int m = 0; m < 4; ++m)
#pragma unroll
    for (int n = 0; n < 4; ++n) acc[m][n] = (floatx4)0.f;

  const char* AsC = (const char*)As;
  const char* BsC = (const char*)Bs;

  for (int k0 = 0; k0 < DM; k0 += 32) {
    if (k0) __syncthreads();
#pragma unroll
    for (int i = 0; i < 2; ++i) {
      int u = w * 2 + i;
      gload16(A + (size_t)(m0 + srow_[i]) * DM + k0 + skof_[i], (char*)As + u * 1024);
      gload16(W + (size_t)(n0 + srow_[i]) * DM + k0 + skof_[i], (char*)Bs + u * 1024);
    }
    __syncthreads();

    half8 af[4], bf[4];
#pragma unroll
    for (int m = 0; m < 4; ++m) af[m] = *(const half8*)(AsC + aoff[m]);
#pragma unroll
    for (int n = 0; n < 4; ++n) bf[n] = *(const half8*)(BsC + boff[n]);
#pragma unroll
    for (int m = 0; m < 4; ++m)
#pragma unroll
      for (int n = 0; n < 4; ++n)
        acc[m][n] = __builtin_amdgcn_mfma_f32_16x16x32_f16(af[m], bf[n], acc[m][n], 0, 0, 0);
  }

#pragma unroll
  for (int m = 0; m < 4; ++m)
#pragma unroll
    for (int n = 0; n < 4; ++n)
#pragma unroll
      for (int j = 0; j < 4; ++j) {
        int rt = wrow + m * 16 + ls * 4 + j;
        int ct = wcol + n * 16 + lr;
        float v = acc[m][n][j] * sin_s + bias[n0 + ct];
        if (RES) v += resid[(size_t)(m0 + rt) * DM + n0 + ct];
        if (ACT == ACT_ELU1) v = (v > 0.f) ? (v + 1.f) : expf(v);
        acc[m][n][j] = v;
      }
  if (REMAP == REMAP_F2O) __syncthreads();

#pragma unroll
  for (int m = 0; m < 4; ++m)
#pragma unroll
    for (int n = 0; n < 4; ++n)
#pragma unroll
      for (int j = 0; j < 4; ++j) {
        int rt = wrow + m * 16 + ls * 4 + j;
        int ct = wcol + n * 16 + lr;
        int mg = m0 + rt, ng = n0 + ct;
        int srw;
        if (REMAP == REMAP_NONE) {
          srw = mg;
        } else if (REMAP == REMAP_A2F) {
          int b = mg >> 7, fg = (mg >> 5) & 3, ant = mg & 31;
          srw = b * 128 + ant * 4 + fg;
        } else {
          int b = mg >> 7, ant = (mg >> 2) & 31, fg = mg & 3;
          srw = b * 128 + fg * 32 + ant;
        }
        float v = acc[m][n][j];
        if (OF32) Cf[(size_t)srw * DM + ng] = v;
        if (OF16) Ch[(size_t)srw * DM + ng] = (_Float16)(v * sout_s);
      }
}

// ---------------- stage-1 linattn: L=32, one block per (g,h) ----------------
// att = (Q K^T) V ; S in fp32 LDS; fp16 I/O; att overwrites Q slice; store*sout.
__global__ __launch_bounds__(256) void linattn32_k(
    _Float16* __restrict__ Q, const _Float16* __restrict__ K,
    const _Float16* __restrict__ V, float sout)
{
  __shared__ _Float16 Qs[32][64];   // swizzled: chunk ^= (row&7)*8
  __shared__ _Float16 Ks[32][64];   // swizzled: chunk ^= ((row>>2)&7)*8
  __shared__ _Float16 Vs[32][64];   // linear
  __shared__ float Ss[32][33];

  const int g = blockIdx.x, h = blockIdx.y;
  const size_t base = (size_t)g * 32 * DM + h * 64;
  const int t = threadIdx.x;

  {  // load: thread -> (row, 8-half chunk)
    const int row = t >> 3, ch = (t & 7) * 8;
    half8 q8 = *(const half8*)(Q + base + (size_t)row * DM + ch);
    half8 k8 = *(const half8*)(K + base + (size_t)row * DM + ch);
    half8 v8 = *(const half8*)(V + base + (size_t)row * DM + ch);
    *(half8*)&Qs[row][ch ^ ((row & 7) * 8)] = q8;
    *(half8*)&Ks[row][ch ^ (((row >> 2) & 7) * 8)] = k8;
    *(half8*)&Vs[row][ch] = v8;
  }
  __syncthreads();

  {  // S[t][s] = Q[t] . K[s] ; thread -> (tt, 4 s's)
    const int tt = t >> 3, sg = t & 7;
    const int xq = (tt & 7) * 8, xk = sg * 8;
    float acc[4] = {};
#pragma unroll
    for (int jj = 0; jj < 32; ++jj) {
      h2 qq = *(const h2*)&Qs[tt][(2 * jj) ^ xq];
#pragma unroll
      for (int si = 0; si < 4; ++si) {
        h2 kk = *(const h2*)&Ks[sg * 4 + si][(2 * jj) ^ xk];
        acc[si] = fdot2f(qq, kk, acc[si]);
      }
    }
#pragma unroll
    for (int si = 0; si < 4; ++si) Ss[tt][sg * 4 + si] = acc[si];
  }
  __syncthreads();

  {  // att[t][e] = sum_s S[t][s] V[s][e] ; thread -> (tt, 8 e's)
    const int tt = t >> 3, e0 = (t & 7) * 8;
    float o[8] = {};
#pragma unroll
    for (int s = 0; s < 32; ++s) {
      float sv = Ss[tt][s];
      half8 vv = *(const half8*)&Vs[s][e0];
#pragma unroll
      for (int e = 0; e < 8; ++e) o[e] = fmaf(sv, (float)vv[e], o[e]);
    }
    half8 r;
#pragma unroll
    for (int e = 0; e < 8; ++e) r[e] = (_Float16)(o[e] * sout);
    *(half8*)(Q + base + (size_t)tt * DM + e0) = r;
  }
}

// ---------------- stage-2 linattn: L=4, one block per batch (16 heads) -------
__global__ __launch_bounds__(256) void linattn4_k(
    _Float16* __restrict__ Q, const _Float16* __restrict__ K,
    const _Float16* __restrict__ V, float sout)
{
  __shared__ _Float16 Qs[4][1024];  // per-head swizzle: chunk ^= (h&7)*8
  __shared__ _Float16 Ks[4][1024];
  __shared__ _Float16 Vs[4][1024];
  __shared__ float Ss[16][4][5];    // [h][t][s], padded

  const int g = blockIdx.x;
  const size_t base = (size_t)g * 4 * DM;
  const int t = threadIdx.x;

  {  // load: thread -> 16 halves per matrix (2 swizzled 8-chunks)
    const int off = t * 16;
    const int row = off >> 10, col = off & 1023;
    const int h = col >> 6, d = col & 63, x = (h & 7) * 8;
    const int c0 = h * 64 + (d ^ x), c1 = h * 64 + ((d + 8) ^ x);
    half8 q0 = *(const half8*)(Q + base + off);
    half8 q1 = *(const half8*)(Q + base + off + 8);
    half8 k0 = *(const half8*)(K + base + off);
    half8 k1 = *(const half8*)(K + base + off + 8);
    half8 v0 = *(const half8*)(V + base + off);
    half8 v1 = *(const half8*)(V + base + off + 8);
    *(half8*)&Qs[row][c0] = q0; *(half8*)&Qs[row][c1] = q1;
    *(half8*)&Ks[row][c0] = k0; *(half8*)&Ks[row][c1] = k1;
    *(half8*)&Vs[row][c0] = v0; *(half8*)&Vs[row][c1] = v1;
  }
  __syncthreads();

  {  // S[h][t][s]: one 64-dot per thread
    const int h = t >> 4, tt = (t >> 2) & 3, s = t & 3;
    const int x = (h & 7) * 8;
    const _Float16* qp = &Qs[tt][h * 64];
    const _Float16* kp = &Ks[s][h * 64];
    float acc = 0.f;
#pragma unroll
    for (int jj = 0; jj < 32; ++jj) {
      int dd = (2 * jj) ^ x;
      acc = fdot2f(*(const h2*)(qp + dd), *(const h2*)(kp + dd), acc);
    }
    Ss[h][tt][s] = acc;
  }
  __syncthreads();

  {  // att[t][h*64+e] = sum_s S[h][t][s] V[s][h*64+e] ; thread -> 16 cols
    const int tt = t >> 6, cg = t & 63;
    const int h = cg >> 2, e0 = (cg & 3) * 16, x = (h & 7) * 8;
    const float* sp = Ss[h][tt];
    float o[16] = {};
#pragma unroll
    for (int s = 0; s < 4; ++s) {
      float sv = sp[s];
      half8 va = *(const half8*)&Vs[s][h * 64 + (e0 ^ x)];
      half8 vb = *(const half8*)&Vs[s][h * 64 + ((e0 + 8) ^ x)];
#pragma unroll
      for (int e = 0; e < 8; ++e) {
        o[e]     = fmaf(sv, (float)va[e], o[e]);
        o[e + 8] = fmaf(sv, (float)vb[e], o[e + 8]);
      }
    }
    half8 r0, r1;
#pragma unroll
    for (int e = 0; e < 8; ++e) {
      r0[e] = (_Float16)(o[e] * sout);
      r1[e] = (_Float16)(o[e + 8] * sout);
    }
    _Float16* dst = Q + base + (size_t)tt * DM + h * 64 + e0;
    *(half8*)dst = r0;
    *(half8*)(dst + 8) = r1;
  }
}

// ---------------- small prep kernels ----------------
__global__ __launch_bounds__(256) void transpose_w_k(
    const float* __restrict__ W, _Float16* __restrict__ Wt)
{
  __shared__ float tile[32][33];
  const int tx = threadIdx.x & 31, ty = threadIdx.x >> 5;
  const int k0 = blockIdx.x * 32, n0 = blockIdx.y * 32;
#pragma unroll
  for (int r = 0; r < 4; ++r)
    tile[ty + r * 8][tx] = W[(size_t)(k0 + ty + r * 8) * DM + n0 + tx];
  __syncthreads();
#pragma unroll
  for (int r = 0; r < 4; ++r)
    Wt[(size_t)(n0 + ty + r * 8) * DM + k0 + tx] = (_Float16)tile[tx][ty + r * 8];
}

__global__ __launch_bounds__(256) void convf2h_k(
    const float* __restrict__ x, _Float16* __restrict__ xh, int n8)
{
  for (int i = blockIdx.x * blockDim.x + threadIdx.x; i < n8;
       i += gridDim.x * blockDim.x) {
    float4 a = ((const float4*)x)[i * 2];
    float4 b = ((const float4*)x)[i * 2 + 1];
    half8 h;
    h[0] = (_Float16)a.x; h[1] = (_Float16)a.y; h[2] = (_Float16)a.z; h[3] = (_Float16)a.w;
    h[4] = (_Float16)b.x; h[5] = (_Float16)b.y; h[6] = (_Float16)b.z; h[7] = (_Float16)b.w;
    ((half8*)xh)[i] = h;
  }
}

extern "C" void kernel_launch(void* const* d_in, const int* in_sizes, int n_in,
                              void* d_out, int out_size, void* d_ws, size_t ws_size,
                              hipStream_t stream)
{
  const float* x   = (const float*)d_in[0];
  const float* wsrc[8] = {(const float*)d_in[1], (const float*)d_in[3],
                          (const float*)d_in[5], (const float*)d_in[7],
                          (const float*)d_in[9], (const float*)d_in[11],
                          (const float*)d_in[13], (const float*)d_in[15]};
  const float* aqb = (const float*)d_in[2];  const float* akb = (const float*)d_in[4];
  const float* avb = (const float*)d_in[6];  const float* aob = (const float*)d_in[8];
  const float* fqb = (const float*)d_in[10]; const float* fkb = (const float*)d_in[12];
  const float* fvb = (const float*)d_in[14]; const float* fob = (const float*)d_in[16];
  float* out = (float*)d_out;

  const size_t NE = (size_t)MTOT * DM;
  _Float16* xh = (_Float16*)d_ws;     // reused as X2h after stage 1
  _Float16* Qh = xh + NE;             // att overwrites Q in place
  _Float16* Kh = Qh + NE;
  _Float16* Vh = Kh + NE;
  _Float16* wt = Vh + NE;             // 8 x 1M halves
  const size_t WSZ = (size_t)DM * DM;

  dim3 gg(MTOT / 128, DM / 128), gb(256);
  dim3 tg(32, 32);

  convf2h_k<<<2048, gb, 0, stream>>>(x, xh, (int)(NE / 8));
  for (int j = 0; j < 8; ++j)
    transpose_w_k<<<tg, gb, 0, stream>>>(wsrc[j], wt + WSZ * j);

  const float S = 0.0625f;  // 2^-4

  // ----- stage 1: antenna attention -----
  gemm_k<ACT_ELU1, REMAP_NONE, false, false, true><<<gg, gb, 0, stream>>>(
      xh, wt + WSZ * 0, aqb, nullptr, nullptr, Qh, 1.f, 1.f);
  gemm_k<ACT_ELU1, REMAP_NONE, false, false, true><<<gg, gb, 0, stream>>>(
      xh, wt + WSZ * 1, akb, nullptr, nullptr, Kh, 1.f, 1.f);
  gemm_k<ACT_NONE, REMAP_NONE, false, false, true><<<gg, gb, 0, stream>>>(
      xh, wt + WSZ * 2, avb, nullptr, nullptr, Vh, 1.f, 1.f);
  linattn32_k<<<dim3(1024, 16), gb, 0, stream>>>(Qh, Kh, Vh, S);
  gemm_k<ACT_NONE, REMAP_A2F, true, true, true><<<gg, gb, 0, stream>>>(
      Qh, wt + WSZ * 3, aob, x, out, xh, 16.f, S);

  // ----- stage 2: frequency attention -----
  gemm_k<ACT_ELU1, REMAP_NONE, false, false, true><<<gg, gb, 0, stream>>>(
      xh, wt + WSZ * 4, fqb, nullptr, nullptr, Qh, 16.f, S);
  gemm_k<ACT_ELU1, REMAP_NONE, false, false, true><<<gg, gb, 0, stream>>>(
      xh, wt + WSZ * 5, fkb, nullptr, nullptr, Kh, 16.f, S);
  gemm_k<ACT_NONE, REMAP_NONE, false, false, true><<<gg, gb, 0, stream>>>(
      xh, wt + WSZ * 6, fvb, nullptr, nullptr, Vh, 16.f, S);
  linattn4_k<<<8192, gb, 0, stream>>>(Qh, Kh, Vh, S);
  gemm_k<ACT_NONE, REMAP_F2O, true, true, false><<<gg, gb, 0, stream>>>(
      Qh, wt + WSZ * 7, fob, out, out, nullptr, 65536.f, 1.f);
}

// Round 4
// 1080.019 us; speedup vs baseline: 6.2862x; 1.1015x over previous
//
#include <hip/hip_runtime.h>
#include <math.h>

// AxialLinearAttention — fp16 MFMA GEMMs + re-associated (QK^T)V linear attention.
// B=256, FG=4, ANT=32, D=1024, H=16, DK=64. M = 32768 rows for every GEMM.
// Scale bookkeeping (all powers of 2, exact):
//   xh = x (fp16, scale 1); Q1,K1,V1 scale 1; att1 stored * 2^-4
//   X2h = X2 * 2^-4 (fp16, overwrites xh in place); Q2,K2,V2 stored * 2^-4
//   att2 stored * 2^-16; final out = 2^16 * acc + bias + 16 * X2h  (fp32)

#define MTOT 32768
#define DM 1024

using half8   = __attribute__((ext_vector_type(8))) _Float16;
using h2      = __attribute__((ext_vector_type(2))) _Float16;
using floatx4 = __attribute__((ext_vector_type(4))) float;

#define ACT_NONE 0
#define ACT_ELU1 1
#define REMAP_NONE 0
#define REMAP_A2F 1   // (b,fg,ant) -> (b,ant,fg)
#define REMAP_F2O 2   // (b,ant,fg) -> (b,fg,ant)

__device__ __forceinline__ void gload16(const void* g, void* lds) {
  __builtin_amdgcn_global_load_lds(
      (const __attribute__((address_space(1))) unsigned int*)g,
      (__attribute__((address_space(3))) unsigned int*)lds, 16, 0, 0);
}

__device__ __forceinline__ float fdot2f(h2 a, h2 b, float c) {
#if __has_builtin(__builtin_amdgcn_fdot2)
  return __builtin_amdgcn_fdot2(a, b, c, false);
#else
  return fmaf((float)a[0], (float)b[0], fmaf((float)a[1], (float)b[1], c));
#endif
}

// ---------------- GEMM ----------------
// C = act(sin_s * (A @ Wt^T) + bias [+ rs*resid16]); rows remapped on store.
// A: [M][1024] fp16 K-major. Wt: [N][1024] fp16 K-major (pre-transposed W).
// 128x128 tile, BK=32, 256 threads (4 waves), wave -> 64x64, mfma 16x16x32 f16.
// In-place remap (C==resid buffer) is safe: each (b-block, col-block) tile is
// block-private under the row permutation; pre-store __syncthreads orders the
// intra-block resid reads before the permuted writes.
template<int ACT, int REMAP, bool RES, bool OF32, bool OF16>
__global__ __launch_bounds__(256) void gemm_k(
    const _Float16* __restrict__ A, const _Float16* __restrict__ W,
    const float* __restrict__ bias, const _Float16* __restrict__ resid,
    float rs, float* __restrict__ Cf, _Float16* __restrict__ Ch,
    float sin_s, float sout_s)
{
  __shared__ _Float16 As[4096];
  __shared__ _Float16 Bs[4096];

  const int t = threadIdx.x, w = t >> 6, l = t & 63;
  const int m0 = blockIdx.x * 128, n0 = blockIdx.y * 128;
  const int lr = l & 15, ls = l >> 4;
  const int wrow = (w >> 1) * 64, wcol = (w & 1) * 64;

  int srow_[2], skof_[2];
#pragma unroll
  for (int i = 0; i < 2; ++i) {
    int u = w * 2 + i;
    int row = u * 16 + (l >> 2);
    srow_[i] = row;
    skof_[i] = ((l & 3) ^ ((row >> 1) & 3)) * 8;
  }
  int aoff[4], boff[4];
#pragma unroll
  for (int m = 0; m < 4; ++m) {
    int ra = wrow + m * 16 + lr;
    aoff[m] = ra * 64 + ((ls ^ ((ra >> 1) & 3)) << 4);
    int rb = wcol + m * 16 + lr;
    boff[m] = rb * 64 + ((ls ^ ((rb >> 1) & 3)) << 4);
  }

  floatx4 acc[4][4];
#pragma unroll
  for (int m = 0; m < 4; ++m)
#pragma unroll
    for (int n = 0; n < 4; ++n) acc[m][n] = (floatx4)0.f;

  const char* AsC = (const char*)As;
  const char* BsC = (const char*)Bs;

  for (int k0 = 0; k0 < DM; k0 += 32) {
    if (k0) __syncthreads();
#pragma unroll
    for (int i = 0; i < 2; ++i) {
      int u = w * 2 + i;
      gload16(A + (size_t)(m0 + srow_[i]) * DM + k0 + skof_[i], (char*)As + u * 1024);
      gload16(W + (size_t)(n0 + srow_[i]) * DM + k0 + skof_[i], (char*)Bs + u * 1024);
    }
    __syncthreads();

    half8 af[4], bf[4];
#pragma unroll
    for (int m = 0; m < 4; ++m) af[m] = *(const half8*)(AsC + aoff[m]);
#pragma unroll
    for (int n = 0; n < 4; ++n) bf[n] = *(const half8*)(BsC + boff[n]);
#pragma unroll
    for (int m = 0; m < 4; ++m)
#pragma unroll
      for (int n = 0; n < 4; ++n)
        acc[m][n] = __builtin_amdgcn_mfma_f32_16x16x32_f16(af[m], bf[n], acc[m][n], 0, 0, 0);
  }

  // epilogue phase 1: finalize values in acc (C/D map: row=(l>>4)*4+j, col=l&15)
#pragma unroll
  for (int m = 0; m < 4; ++m)
#pragma unroll
    for (int n = 0; n < 4; ++n)
#pragma unroll
      for (int j = 0; j < 4; ++j) {
        int rt = wrow + m * 16 + ls * 4 + j;
        int ct = wcol + n * 16 + lr;
        float v = acc[m][n][j] * sin_s + bias[n0 + ct];
        if (RES) v += rs * (float)resid[(size_t)(m0 + rt) * DM + n0 + ct];
        if (ACT == ACT_ELU1) v = (v > 0.f) ? (v + 1.f) : expf(v);
        acc[m][n][j] = v;
      }
  // order all resid reads before any (possibly in-place, row-permuted) store
  if (RES && REMAP != REMAP_NONE) __syncthreads();

#pragma unroll
  for (int m = 0; m < 4; ++m)
#pragma unroll
    for (int n = 0; n < 4; ++n)
#pragma unroll
      for (int j = 0; j < 4; ++j) {
        int rt = wrow + m * 16 + ls * 4 + j;
        int ct = wcol + n * 16 + lr;
        int mg = m0 + rt, ng = n0 + ct;
        int srw;
        if (REMAP == REMAP_NONE) {
          srw = mg;
        } else if (REMAP == REMAP_A2F) {
          int b = mg >> 7, fg = (mg >> 5) & 3, ant = mg & 31;
          srw = b * 128 + ant * 4 + fg;
        } else {
          int b = mg >> 7, ant = (mg >> 2) & 31, fg = mg & 3;
          srw = b * 128 + fg * 32 + ant;
        }
        float v = acc[m][n][j];
        if (OF32) Cf[(size_t)srw * DM + ng] = v;
        if (OF16) Ch[(size_t)srw * DM + ng] = (_Float16)(v * sout_s);
      }
}

// ---------------- stage-1 linattn: L=32, one block per (g,h) ----------------
__global__ __launch_bounds__(256) void linattn32_k(
    _Float16* __restrict__ Q, const _Float16* __restrict__ K,
    const _Float16* __restrict__ V, float sout)
{
  __shared__ _Float16 Qs[32][64];   // swizzled: chunk ^= (row&7)*8
  __shared__ _Float16 Ks[32][64];   // swizzled: chunk ^= ((row>>2)&7)*8
  __shared__ _Float16 Vs[32][64];   // linear
  __shared__ float Ss[32][33];

  const int g = blockIdx.x, h = blockIdx.y;
  const size_t base = (size_t)g * 32 * DM + h * 64;
  const int t = threadIdx.x;

  {
    const int row = t >> 3, ch = (t & 7) * 8;
    half8 q8 = *(const half8*)(Q + base + (size_t)row * DM + ch);
    half8 k8 = *(const half8*)(K + base + (size_t)row * DM + ch);
    half8 v8 = *(const half8*)(V + base + (size_t)row * DM + ch);
    *(half8*)&Qs[row][ch ^ ((row & 7) * 8)] = q8;
    *(half8*)&Ks[row][ch ^ (((row >> 2) & 7) * 8)] = k8;
    *(half8*)&Vs[row][ch] = v8;
  }
  __syncthreads();

  {  // S[t][s] = Q[t] . K[s] ; thread -> (tt, 4 s's)
    const int tt = t >> 3, sg = t & 7;
    const int xq = (tt & 7) * 8, xk = sg * 8;
    float acc[4] = {};
#pragma unroll
    for (int jj = 0; jj < 32; ++jj) {
      h2 qq = *(const h2*)&Qs[tt][(2 * jj) ^ xq];
#pragma unroll
      for (int si = 0; si < 4; ++si) {
        h2 kk = *(const h2*)&Ks[sg * 4 + si][(2 * jj) ^ xk];
        acc[si] = fdot2f(qq, kk, acc[si]);
      }
    }
#pragma unroll
    for (int si = 0; si < 4; ++si) Ss[tt][sg * 4 + si] = acc[si];
  }
  __syncthreads();

  {  // att[t][e] = sum_s S[t][s] V[s][e] ; thread -> (tt, 8 e's)
    const int tt = t >> 3, e0 = (t & 7) * 8;
    float o[8] = {};
#pragma unroll
    for (int s = 0; s < 32; ++s) {
      float sv = Ss[tt][s];
      half8 vv = *(const half8*)&Vs[s][e0];
#pragma unroll
      for (int e = 0; e < 8; ++e) o[e] = fmaf(sv, (float)vv[e], o[e]);
    }
    half8 r;
#pragma unroll
    for (int e = 0; e < 8; ++e) r[e] = (_Float16)(o[e] * sout);
    *(half8*)(Q + base + (size_t)tt * DM + e0) = r;
  }
}

// ---------------- stage-2 linattn: L=4, one block per batch (16 heads) -------
__global__ __launch_bounds__(256) void linattn4_k(
    _Float16* __restrict__ Q, const _Float16* __restrict__ K,
    const _Float16* __restrict__ V, float sout)
{
  __shared__ _Float16 Qs[4][1024];  // per-head swizzle: chunk ^= (h&7)*8
  __shared__ _Float16 Ks[4][1024];
  __shared__ _Float16 Vs[4][1024];
  __shared__ float Ss[16][4][5];

  const int g = blockIdx.x;
  const size_t base = (size_t)g * 4 * DM;
  const int t = threadIdx.x;

  {
    const int off = t * 16;
    const int row = off >> 10, col = off & 1023;
    const int h = col >> 6, d = col & 63, x = (h & 7) * 8;
    const int c0 = h * 64 + (d ^ x), c1 = h * 64 + ((d + 8) ^ x);
    half8 q0 = *(const half8*)(Q + base + off);
    half8 q1 = *(const half8*)(Q + base + off + 8);
    half8 k0 = *(const half8*)(K + base + off);
    half8 k1 = *(const half8*)(K + base + off + 8);
    half8 v0 = *(const half8*)(V + base + off);
    half8 v1 = *(const half8*)(V + base + off + 8);
    *(half8*)&Qs[row][c0] = q0; *(half8*)&Qs[row][c1] = q1;
    *(half8*)&Ks[row][c0] = k0; *(half8*)&Ks[row][c1] = k1;
    *(half8*)&Vs[row][c0] = v0; *(half8*)&Vs[row][c1] = v1;
  }
  __syncthreads();

  {  // S[h][t][s]: one 64-dot per thread
    const int h = t >> 4, tt = (t >> 2) & 3, s = t & 3;
    const int x = (h & 7) * 8;
    const _Float16* qp = &Qs[tt][h * 64];
    const _Float16* kp = &Ks[s][h * 64];
    float acc = 0.f;
#pragma unroll
    for (int jj = 0; jj < 32; ++jj) {
      int dd = (2 * jj) ^ x;
      acc = fdot2f(*(const h2*)(qp + dd), *(const h2*)(kp + dd), acc);
    }
    Ss[h][tt][s] = acc;
  }
  __syncthreads();

  {  // att[t][h*64+e] = sum_s S[h][t][s] V[s][h*64+e] ; thread -> 16 cols
    const int tt = t >> 6, cg = t & 63;
    const int h = cg >> 2, e0 = (cg & 3) * 16, x = (h & 7) * 8;
    const float* sp = Ss[h][tt];
    float o[16] = {};
#pragma unroll
    for (int s = 0; s < 4; ++s) {
      float sv = sp[s];
      half8 va = *(const half8*)&Vs[s][h * 64 + (e0 ^ x)];
      half8 vb = *(const half8*)&Vs[s][h * 64 + ((e0 + 8) ^ x)];
#pragma unroll
      for (int e = 0; e < 8; ++e) {
        o[e]     = fmaf(sv, (float)va[e], o[e]);
        o[e + 8] = fmaf(sv, (float)vb[e], o[e + 8]);
      }
    }
    half8 r0, r1;
#pragma unroll
    for (int e = 0; e < 8; ++e) {
      r0[e] = (_Float16)(o[e] * sout);
      r1[e] = (_Float16)(o[e + 8] * sout);
    }
    _Float16* dst = Q + base + (size_t)tt * DM + h * 64 + e0;
    *(half8*)dst = r0;
    *(half8*)(dst + 8) = r1;
  }
}

// ---------------- small prep kernels ----------------
__global__ __launch_bounds__(256) void transpose_w_k(
    const float* __restrict__ W, _Float16* __restrict__ Wt)
{
  __shared__ float tile[32][33];
  const int tx = threadIdx.x & 31, ty = threadIdx.x >> 5;
  const int k0 = blockIdx.x * 32, n0 = blockIdx.y * 32;
#pragma unroll
  for (int r = 0; r < 4; ++r)
    tile[ty + r * 8][tx] = W[(size_t)(k0 + ty + r * 8) * DM + n0 + tx];
  __syncthreads();
#pragma unroll
  for (int r = 0; r < 4; ++r)
    Wt[(size_t)(n0 + ty + r * 8) * DM + k0 + tx] = (_Float16)tile[tx][ty + r * 8];
}

__global__ __launch_bounds__(256) void convf2h_k(
    const float* __restrict__ x, _Float16* __restrict__ xh, int n8)
{
  for (int i = blockIdx.x * blockDim.x + threadIdx.x; i < n8;
       i += gridDim.x * blockDim.x) {
    float4 a = ((const float4*)x)[i * 2];
    float4 b = ((const float4*)x)[i * 2 + 1];
    half8 h;
    h[0] = (_Float16)a.x; h[1] = (_Float16)a.y; h[2] = (_Float16)a.z; h[3] = (_Float16)a.w;
    h[4] = (_Float16)b.x; h[5] = (_Float16)b.y; h[6] = (_Float16)b.z; h[7] = (_Float16)b.w;
    ((half8*)xh)[i] = h;
  }
}

extern "C" void kernel_launch(void* const* d_in, const int* in_sizes, int n_in,
                              void* d_out, int out_size, void* d_ws, size_t ws_size,
                              hipStream_t stream)
{
  const float* x   = (const float*)d_in[0];
  const float* wsrc[8] = {(const float*)d_in[1], (const float*)d_in[3],
                          (const float*)d_in[5], (const float*)d_in[7],
                          (const float*)d_in[9], (const float*)d_in[11],
                          (const float*)d_in[13], (const float*)d_in[15]};
  const float* aqb = (const float*)d_in[2];  const float* akb = (const float*)d_in[4];
  const float* avb = (const float*)d_in[6];  const float* aob = (const float*)d_in[8];
  const float* fqb = (const float*)d_in[10]; const float* fkb = (const float*)d_in[12];
  const float* fvb = (const float*)d_in[14]; const float* fob = (const float*)d_in[16];
  float* out = (float*)d_out;

  const size_t NE = (size_t)MTOT * DM;
  _Float16* xh = (_Float16*)d_ws;     // holds x, then X2h (in-place remap)
  _Float16* Qh = xh + NE;             // att overwrites Q in place
  _Float16* Kh = Qh + NE;
  _Float16* Vh = Kh + NE;
  _Float16* wt = Vh + NE;             // 8 x 1M halves
  const size_t WSZ = (size_t)DM * DM;

  dim3 gg(MTOT / 128, DM / 128), gb(256);
  dim3 tg(32, 32);

  convf2h_k<<<2048, gb, 0, stream>>>(x, xh, (int)(NE / 8));
  for (int j = 0; j < 8; ++j)
    transpose_w_k<<<tg, gb, 0, stream>>>(wsrc[j], wt + WSZ * j);

  const float S = 0.0625f;  // 2^-4

  // ----- stage 1: antenna attention -----
  gemm_k<ACT_ELU1, REMAP_NONE, false, false, true><<<gg, gb, 0, stream>>>(
      xh, wt + WSZ * 0, aqb, nullptr, 0.f, nullptr, Qh, 1.f, 1.f);
  gemm_k<ACT_ELU1, REMAP_NONE, false, false, true><<<gg, gb, 0, stream>>>(
      xh, wt + WSZ * 1, akb, nullptr, 0.f, nullptr, Kh, 1.f, 1.f);
  gemm_k<ACT_NONE, REMAP_NONE, false, false, true><<<gg, gb, 0, stream>>>(
      xh, wt + WSZ * 2, avb, nullptr, 0.f, nullptr, Vh, 1.f, 1.f);
  linattn32_k<<<dim3(1024, 16), gb, 0, stream>>>(Qh, Kh, Vh, S);
  // X2h = (x + att1*2^4 @ Wout) * 2^-4, rows -> (b,ant,fg), in place over xh
  gemm_k<ACT_NONE, REMAP_A2F, true, false, true><<<gg, gb, 0, stream>>>(
      Qh, wt + WSZ * 3, aob, xh, 1.f, nullptr, xh, 16.f, S);

  // ----- stage 2: frequency attention -----
  gemm_k<ACT_ELU1, REMAP_NONE, false, false, true><<<gg, gb, 0, stream>>>(
      xh, wt + WSZ * 4, fqb, nullptr, 0.f, nullptr, Qh, 16.f, S);
  gemm_k<ACT_ELU1, REMAP_NONE, false, false, true><<<gg, gb, 0, stream>>>(
      xh, wt + WSZ * 5, fkb, nullptr, 0.f, nullptr, Kh, 16.f, S);
  gemm_k<ACT_NONE, REMAP_NONE, false, false, true><<<gg, gb, 0, stream>>>(
      xh, wt + WSZ * 6, fvb, nullptr, 0.f, nullptr, Vh, 16.f, S);
  linattn4_k<<<8192, gb, 0, stream>>>(Qh, Kh, Vh, S);
  // out = 2^16 * (att2 @ Wout2) + bias + 16*X2h, rows back to (b,fg,ant), fp32
  gemm_k<ACT_NONE, REMAP_F2O, true, true, false><<<gg, gb, 0, stream>>>(
      Qh, wt + WSZ * 7, fob, xh, 16.f, out, nullptr, 65536.f, 1.f);
}

// Round 5
// 969.790 us; speedup vs baseline: 7.0007x; 1.1137x over previous
//
#include <hip/hip_runtime.h>
#include <math.h>

// AxialLinearAttention — fp16 MFMA GEMMs (BK=64, XCD-swizzled) + (QK^T)V linattn.
// B=256, FG=4, ANT=32, D=1024, H=16, DK=64. M = 32768 rows for every GEMM.
// Scale bookkeeping (all powers of 2, exact):
//   xh = x (fp16, scale 1); Q1,K1,V1 scale 1; att1 stored * 2^-4
//   X2h = X2 * 2^-4 (fp16, overwrites xh in place); Q2,K2,V2 stored * 2^-4
//   att2 stored * 2^-16; final out = 2^16 * acc + bias + 16 * X2h  (fp32)

#define MTOT 32768
#define DM 1024

using half8   = __attribute__((ext_vector_type(8))) _Float16;
using h2      = __attribute__((ext_vector_type(2))) _Float16;
using floatx4 = __attribute__((ext_vector_type(4))) float;

#define ACT_NONE 0
#define ACT_ELU1 1
#define REMAP_NONE 0
#define REMAP_A2F 1   // (b,fg,ant) -> (b,ant,fg)
#define REMAP_F2O 2   // (b,ant,fg) -> (b,fg,ant)

__device__ __forceinline__ void gload16(const void* g, void* lds) {
  __builtin_amdgcn_global_load_lds(
      (const __attribute__((address_space(1))) unsigned int*)g,
      (__attribute__((address_space(3))) unsigned int*)lds, 16, 0, 0);
}

__device__ __forceinline__ float fdot2f(h2 a, h2 b, float c) {
#if __has_builtin(__builtin_amdgcn_fdot2)
  return __builtin_amdgcn_fdot2(a, b, c, false);
#else
  return fmaf((float)a[0], (float)b[0], fmaf((float)a[1], (float)b[1], c));
#endif
}

// ---------------- GEMM ----------------
// C = act(sin_s * (A @ Wt^T) + bias [+ rs*resid16]); rows remapped on store.
// A: [M][1024] fp16 K-major. Wt: [N][1024] fp16 K-major (pre-transposed W).
// 128x128 tile, BK=64, 256 threads (4 waves), wave -> 64x64, mfma 16x16x32 f16.
// LDS tile [128 rows][64 k] fp16 (128B rows = 8 x 16B slots).
// Swizzle: global k-slot s stored at LDS slot s ^ (row&7); achieved by
// pre-swizzling the global SOURCE (linear LDS dest, rule #21) and XORing on
// the ds_read address. Within each 8-lane b128 phase all 8 bank-quads hit
// exactly once -> conflict-free.
template<int ACT, int REMAP, bool RES, bool OF32, bool OF16>
__global__ __launch_bounds__(256) void gemm_k(
    const _Float16* __restrict__ A, const _Float16* __restrict__ W,
    const float* __restrict__ bias, const _Float16* __restrict__ resid,
    float rs, float* __restrict__ Cf, _Float16* __restrict__ Ch,
    float sin_s, float sout_s)
{
  __shared__ _Float16 As[8192];  // 16 KB
  __shared__ _Float16 Bs[8192];  // 16 KB

  const int t = threadIdx.x, w = t >> 6, l = t & 63;
  // XCD-aware bijective swizzle of the m-tile index (gridDim.x = 256, %8 == 0)
  const int bx = blockIdx.x;
  const int m0 = (((bx & 7) << 5) + (bx >> 3)) * 128;
  const int n0 = blockIdx.y * 128;
  const int lr = l & 15, ls = l >> 4;
  const int wrow = (w >> 1) * 64, wcol = (w & 1) * 64;

  // staging: 16 chunks of 1024B per operand; wave w owns chunks w*4..w*4+3.
  // chunk u: lane lds byte = u*1024 + l*16 -> row = u*8 + (l>>3), slot = l&7.
  // global fetch slot = (l&7) ^ (row&7) = (l&7) ^ ((l>>3)&7)  (u*8 == 0 mod 8)
  const int lrow = l >> 3;
  const int lsl  = ((l & 7) ^ (lrow & 7)) * 8;  // k-offset in halves

  // ds_read frag byte offsets: row ra, k-slot (kk*4+ls) -> ^ (ra&7)
  int aoff[2][4], boff[2][4];
#pragma unroll
  for (int kk = 0; kk < 2; ++kk)
#pragma unroll
    for (int m = 0; m < 4; ++m) {
      int ra = wrow + m * 16 + lr;
      aoff[kk][m] = ra * 128 + (((kk * 4 + ls) ^ (ra & 7)) << 4);
      int rb = wcol + m * 16 + lr;
      boff[kk][m] = rb * 128 + (((kk * 4 + ls) ^ (rb & 7)) << 4);
    }

  floatx4 acc[4][4];
#pragma unroll
  for (int m = 0; m < 4; ++m)
#pragma unroll
    for (int n = 0; n < 4; ++n) acc[m][n] = (floatx4)0.f;

  const char* AsC = (const char*)As;
  const char* BsC = (const char*)Bs;

  for (int k0 = 0; k0 < DM; k0 += 64) {
    if (k0) __syncthreads();
#pragma unroll
    for (int i = 0; i < 4; ++i) {
      int u = w * 4 + i;
      int row = u * 8 + lrow;
      gload16(A + (size_t)(m0 + row) * DM + k0 + lsl, (char*)As + u * 1024);
      gload16(W + (size_t)(n0 + row) * DM + k0 + lsl, (char*)Bs + u * 1024);
    }
    __syncthreads();

#pragma unroll
    for (int kk = 0; kk < 2; ++kk) {
      half8 af[4], bf[4];
#pragma unroll
      for (int m = 0; m < 4; ++m) af[m] = *(const half8*)(AsC + aoff[kk][m]);
#pragma unroll
      for (int n = 0; n < 4; ++n) bf[n] = *(const half8*)(BsC + boff[kk][n]);
#pragma unroll
      for (int m = 0; m < 4; ++m)
#pragma unroll
        for (int n = 0; n < 4; ++n)
          acc[m][n] = __builtin_amdgcn_mfma_f32_16x16x32_f16(af[m], bf[n], acc[m][n], 0, 0, 0);
    }
  }

  // hoist bias (4 distinct values per thread)
  float bb[4];
#pragma unroll
  for (int n = 0; n < 4; ++n) bb[n] = bias[n0 + wcol + n * 16 + lr];

  // epilogue phase 1: finalize values in acc (C/D map: row=(l>>4)*4+j, col=l&15)
#pragma unroll
  for (int m = 0; m < 4; ++m)
#pragma unroll
    for (int n = 0; n < 4; ++n)
#pragma unroll
      for (int j = 0; j < 4; ++j) {
        int rt = wrow + m * 16 + ls * 4 + j;
        int ct = wcol + n * 16 + lr;
        float v = acc[m][n][j] * sin_s + bb[n];
        if (RES) v += rs * (float)resid[(size_t)(m0 + rt) * DM + n0 + ct];
        if (ACT == ACT_ELU1) v = (v > 0.f) ? (v + 1.f) : expf(v);
        acc[m][n][j] = v;
      }
  // order all resid reads before any (possibly in-place, row-permuted) store
  if (RES && REMAP != REMAP_NONE) __syncthreads();

#pragma unroll
  for (int m = 0; m < 4; ++m)
#pragma unroll
    for (int n = 0; n < 4; ++n)
#pragma unroll
      for (int j = 0; j < 4; ++j) {
        int rt = wrow + m * 16 + ls * 4 + j;
        int ct = wcol + n * 16 + lr;
        int mg = m0 + rt, ng = n0 + ct;
        int srw;
        if (REMAP == REMAP_NONE) {
          srw = mg;
        } else if (REMAP == REMAP_A2F) {
          int b = mg >> 7, fg = (mg >> 5) & 3, ant = mg & 31;
          srw = b * 128 + ant * 4 + fg;
        } else {
          int b = mg >> 7, ant = (mg >> 2) & 31, fg = mg & 3;
          srw = b * 128 + fg * 32 + ant;
        }
        float v = acc[m][n][j];
        if (OF32) Cf[(size_t)srw * DM + ng] = v;
        if (OF16) Ch[(size_t)srw * DM + ng] = (_Float16)(v * sout_s);
      }
}

// ---------------- stage-1 linattn: L=32, one block per (g,h) ----------------
__global__ __launch_bounds__(256) void linattn32_k(
    _Float16* __restrict__ Q, const _Float16* __restrict__ K,
    const _Float16* __restrict__ V, float sout)
{
  __shared__ _Float16 Qs[32][64];   // swizzled: chunk ^= (row&7)*8
  __shared__ _Float16 Ks[32][64];   // swizzled: chunk ^= ((row>>2)&7)*8
  __shared__ _Float16 Vs[32][64];   // linear
  __shared__ float Ss[32][33];

  const int g = blockIdx.x, h = blockIdx.y;
  const size_t base = (size_t)g * 32 * DM + h * 64;
  const int t = threadIdx.x;

  {
    const int row = t >> 3, ch = (t & 7) * 8;
    half8 q8 = *(const half8*)(Q + base + (size_t)row * DM + ch);
    half8 k8 = *(const half8*)(K + base + (size_t)row * DM + ch);
    half8 v8 = *(const half8*)(V + base + (size_t)row * DM + ch);
    *(half8*)&Qs[row][ch ^ ((row & 7) * 8)] = q8;
    *(half8*)&Ks[row][ch ^ (((row >> 2) & 7) * 8)] = k8;
    *(half8*)&Vs[row][ch] = v8;
  }
  __syncthreads();

  {  // S[t][s] = Q[t] . K[s] ; thread -> (tt, 4 s's)
    const int tt = t >> 3, sg = t & 7;
    const int xq = (tt & 7) * 8, xk = sg * 8;
    float acc[4] = {};
#pragma unroll
    for (int jj = 0; jj < 32; ++jj) {
      h2 qq = *(const h2*)&Qs[tt][(2 * jj) ^ xq];
#pragma unroll
      for (int si = 0; si < 4; ++si) {
        h2 kk = *(const h2*)&Ks[sg * 4 + si][(2 * jj) ^ xk];
        acc[si] = fdot2f(qq, kk, acc[si]);
      }
    }
#pragma unroll
    for (int si = 0; si < 4; ++si) Ss[tt][sg * 4 + si] = acc[si];
  }
  __syncthreads();

  {  // att[t][e] = sum_s S[t][s] V[s][e] ; thread -> (tt, 8 e's)
    const int tt = t >> 3, e0 = (t & 7) * 8;
    float o[8] = {};
#pragma unroll
    for (int s = 0; s < 32; ++s) {
      float sv = Ss[tt][s];
      half8 vv = *(const half8*)&Vs[s][e0];
#pragma unroll
      for (int e = 0; e < 8; ++e) o[e] = fmaf(sv, (float)vv[e], o[e]);
    }
    half8 r;
#pragma unroll
    for (int e = 0; e < 8; ++e) r[e] = (_Float16)(o[e] * sout);
    *(half8*)(Q + base + (size_t)tt * DM + e0) = r;
  }
}

// ---------------- stage-2 linattn: L=4, one block per batch (16 heads) -------
__global__ __launch_bounds__(256) void linattn4_k(
    _Float16* __restrict__ Q, const _Float16* __restrict__ K,
    const _Float16* __restrict__ V, float sout)
{
  __shared__ _Float16 Qs[4][1024];  // per-head swizzle: chunk ^= (h&7)*8
  __shared__ _Float16 Ks[4][1024];
  __shared__ _Float16 Vs[4][1024];
  __shared__ float Ss[16][4][5];

  const int g = blockIdx.x;
  const size_t base = (size_t)g * 4 * DM;
  const int t = threadIdx.x;

  {
    const int off = t * 16;
    const int row = off >> 10, col = off & 1023;
    const int h = col >> 6, d = col & 63, x = (h & 7) * 8;
    const int c0 = h * 64 + (d ^ x), c1 = h * 64 + ((d + 8) ^ x);
    half8 q0 = *(const half8*)(Q + base + off);
    half8 q1 = *(const half8*)(Q + base + off + 8);
    half8 k0 = *(const half8*)(K + base + off);
    half8 k1 = *(const half8*)(K + base + off + 8);
    half8 v0 = *(const half8*)(V + base + off);
    half8 v1 = *(const half8*)(V + base + off + 8);
    *(half8*)&Qs[row][c0] = q0; *(half8*)&Qs[row][c1] = q1;
    *(half8*)&Ks[row][c0] = k0; *(half8*)&Ks[row][c1] = k1;
    *(half8*)&Vs[row][c0] = v0; *(half8*)&Vs[row][c1] = v1;
  }
  __syncthreads();

  {  // S[h][t][s]: one 64-dot per thread
    const int h = t >> 4, tt = (t >> 2) & 3, s = t & 3;
    const int x = (h & 7) * 8;
    const _Float16* qp = &Qs[tt][h * 64];
    const _Float16* kp = &Ks[s][h * 64];
    float acc = 0.f;
#pragma unroll
    for (int jj = 0; jj < 32; ++jj) {
      int dd = (2 * jj) ^ x;
      acc = fdot2f(*(const h2*)(qp + dd), *(const h2*)(kp + dd), acc);
    }
    Ss[h][tt][s] = acc;
  }
  __syncthreads();

  {  // att[t][h*64+e] = sum_s S[h][t][s] V[s][h*64+e] ; thread -> 16 cols
    const int tt = t >> 6, cg = t & 63;
    const int h = cg >> 2, e0 = (cg & 3) * 16, x = (h & 7) * 8;
    const float* sp = Ss[h][tt];
    float o[16] = {};
#pragma unroll
    for (int s = 0; s < 4; ++s) {
      float sv = sp[s];
      half8 va = *(const half8*)&Vs[s][h * 64 + (e0 ^ x)];
      half8 vb = *(const half8*)&Vs[s][h * 64 + ((e0 + 8) ^ x)];
#pragma unroll
      for (int e = 0; e < 8; ++e) {
        o[e]     = fmaf(sv, (float)va[e], o[e]);
        o[e + 8] = fmaf(sv, (float)vb[e], o[e + 8]);
      }
    }
    half8 r0, r1;
#pragma unroll
    for (int e = 0; e < 8; ++e) {
      r0[e] = (_Float16)(o[e] * sout);
      r1[e] = (_Float16)(o[e + 8] * sout);
    }
    _Float16* dst = Q + base + (size_t)tt * DM + h * 64 + e0;
    *(half8*)dst = r0;
    *(half8*)(dst + 8) = r1;
  }
}

// ---------------- small prep kernels ----------------
struct WPtrs { const float* p[8]; };

__global__ __launch_bounds__(256) void transpose_w8_k(
    WPtrs ws, _Float16* __restrict__ wt)
{
  __shared__ float tile[32][33];
  const float* W = ws.p[blockIdx.z];
  _Float16* Wt = wt + (size_t)DM * DM * blockIdx.z;
  const int tx = threadIdx.x & 31, ty = threadIdx.x >> 5;
  const int k0 = blockIdx.x * 32, n0 = blockIdx.y * 32;
#pragma unroll
  for (int r = 0; r < 4; ++r)
    tile[ty + r * 8][tx] = W[(size_t)(k0 + ty + r * 8) * DM + n0 + tx];
  __syncthreads();
#pragma unroll
  for (int r = 0; r < 4; ++r)
    Wt[(size_t)(n0 + ty + r * 8) * DM + k0 + tx] = (_Float16)tile[tx][ty + r * 8];
}

__global__ __launch_bounds__(256) void convf2h_k(
    const float* __restrict__ x, _Float16* __restrict__ xh, int n8)
{
  for (int i = blockIdx.x * blockDim.x + threadIdx.x; i < n8;
       i += gridDim.x * blockDim.x) {
    float4 a = ((const float4*)x)[i * 2];
    float4 b = ((const float4*)x)[i * 2 + 1];
    half8 h;
    h[0] = (_Float16)a.x; h[1] = (_Float16)a.y; h[2] = (_Float16)a.z; h[3] = (_Float16)a.w;
    h[4] = (_Float16)b.x; h[5] = (_Float16)b.y; h[6] = (_Float16)b.z; h[7] = (_Float16)b.w;
    ((half8*)xh)[i] = h;
  }
}

extern "C" void kernel_launch(void* const* d_in, const int* in_sizes, int n_in,
                              void* d_out, int out_size, void* d_ws, size_t ws_size,
                              hipStream_t stream)
{
  const float* x   = (const float*)d_in[0];
  WPtrs wp;
  for (int j = 0; j < 8; ++j) wp.p[j] = (const float*)d_in[1 + 2 * j];
  const float* aqb = (const float*)d_in[2];  const float* akb = (const float*)d_in[4];
  const float* avb = (const float*)d_in[6];  const float* aob = (const float*)d_in[8];
  const float* fqb = (const float*)d_in[10]; const float* fkb = (const float*)d_in[12];
  const float* fvb = (const float*)d_in[14]; const float* fob = (const float*)d_in[16];
  float* out = (float*)d_out;

  const size_t NE = (size_t)MTOT * DM;
  _Float16* xh = (_Float16*)d_ws;     // holds x, then X2h (in-place remap)
  _Float16* Qh = xh + NE;             // att overwrites Q in place
  _Float16* Kh = Qh + NE;
  _Float16* Vh = Kh + NE;
  _Float16* wt = Vh + NE;             // 8 x 1M halves
  const size_t WSZ = (size_t)DM * DM;

  dim3 gg(MTOT / 128, DM / 128), gb(256);

  convf2h_k<<<2048, gb, 0, stream>>>(x, xh, (int)(NE / 8));
  transpose_w8_k<<<dim3(32, 32, 8), gb, 0, stream>>>(wp, wt);

  const float S = 0.0625f;  // 2^-4

  // ----- stage 1: antenna attention -----
  gemm_k<ACT_ELU1, REMAP_NONE, false, false, true><<<gg, gb, 0, stream>>>(
      xh, wt + WSZ * 0, aqb, nullptr, 0.f, nullptr, Qh, 1.f, 1.f);
  gemm_k<ACT_ELU1, REMAP_NONE, false, false, true><<<gg, gb, 0, stream>>>(
      xh, wt + WSZ * 1, akb, nullptr, 0.f, nullptr, Kh, 1.f, 1.f);
  gemm_k<ACT_NONE, REMAP_NONE, false, false, true><<<gg, gb, 0, stream>>>(
      xh, wt + WSZ * 2, avb, nullptr, 0.f, nullptr, Vh, 1.f, 1.f);
  linattn32_k<<<dim3(1024, 16), gb, 0, stream>>>(Qh, Kh, Vh, S);
  // X2h = (x + att1*2^4 @ Wout) * 2^-4, rows -> (b,ant,fg), in place over xh
  gemm_k<ACT_NONE, REMAP_A2F, true, false, true><<<gg, gb, 0, stream>>>(
      Qh, wt + WSZ * 3, aob, xh, 1.f, nullptr, xh, 16.f, S);

  // ----- stage 2: frequency attention -----
  gemm_k<ACT_ELU1, REMAP_NONE, false, false, true><<<gg, gb, 0, stream>>>(
      xh, wt + WSZ * 4, fqb, nullptr, 0.f, nullptr, Qh, 16.f, S);
  gemm_k<ACT_ELU1, REMAP_NONE, false, false, true><<<gg, gb, 0, stream>>>(
      xh, wt + WSZ * 5, fkb, nullptr, 0.f, nullptr, Kh, 16.f, S);
  gemm_k<ACT_NONE, REMAP_NONE, false, false, true><<<gg, gb, 0, stream>>>(
      xh, wt + WSZ * 6, fvb, nullptr, 0.f, nullptr, Vh, 16.f, S);
  linattn4_k<<<8192, gb, 0, stream>>>(Qh, Kh, Vh, S);
  // out = 2^16 * (att2 @ Wout2) + bias + 16*X2h, rows back to (b,fg,ant), fp32
  gemm_k<ACT_NONE, REMAP_F2O, true, true, false><<<gg, gb, 0, stream>>>(
      Qh, wt + WSZ * 7, fob, xh, 16.f, out, nullptr, 65536.f, 1.f);
}